// Round 5
// baseline (2102.875 us; speedup 1.0000x reference)
//
#include <hip/hip_runtime.h>
#include <hip/hip_bf16.h>

// ---------------------------------------------------------------------------
// SpatialGATEncoder: 4-layer GATv2, N=100k, E=800k, HID=128, H=4, D=32.
// Round 5:
//  - edge_score: swapped MFMA operands -> C[channel][edge]; each lane owns
//    ONE edge. B-frags (silu(ea@P+b) channels) computed IN REGISTERS
//    (no esilu materialization -- round 4's 205MB buffer blew ws_size).
//  - epilogue: ushort4 xl/xr gathers, float4 coalesced score writes.
//  - aggregate: software-pipelined online softmax.
// ---------------------------------------------------------------------------

using bf16x8 = __attribute__((ext_vector_type(8))) short;
using f32x4  = __attribute__((ext_vector_type(4))) float;

__device__ inline unsigned short f2bf(float x) {
  __hip_bfloat16 h = __float2bfloat16(x);
  return *reinterpret_cast<unsigned short*>(&h);
}
__device__ inline float bf2f(unsigned short u) {
  unsigned int x = ((unsigned int)u) << 16;
  return __uint_as_float(x);
}

// ---------------- CSR build ----------------
__global__ __launch_bounds__(256) void count_kernel(const int* __restrict__ dstv,
                                                    int* __restrict__ deg, int E) {
  int e = blockIdx.x * 256 + threadIdx.x;
  if (e < E) atomicAdd(&deg[dstv[e]], 1);
}

__global__ __launch_bounds__(1024) void scan_kernel(const int* __restrict__ deg,
                                                    int* __restrict__ off,
                                                    int* __restrict__ cursor, int n) {
  __shared__ int wsum[16];
  __shared__ int chunk_base;
  int t = threadIdx.x;
  int lane = t & 63, wid = t >> 6;
  if (t == 0) chunk_base = 0;
  __syncthreads();
  for (int start = 0; start < n; start += 1024) {
    int i = start + t;
    int v = (i < n) ? deg[i] : 0;
    int x = v;
    #pragma unroll
    for (int o = 1; o < 64; o <<= 1) {
      int y = __shfl_up(x, o, 64);
      if (lane >= o) x += y;
    }
    if (lane == 63) wsum[wid] = x;
    __syncthreads();
    if (wid == 0) {
      int w = (lane < 16) ? wsum[lane] : 0;
      #pragma unroll
      for (int o = 1; o < 16; o <<= 1) {
        int y = __shfl_up(w, o, 64);
        if (lane >= o) w += y;
      }
      if (lane < 16) wsum[lane] = w;
    }
    __syncthreads();
    int wbase = (wid == 0) ? 0 : wsum[wid - 1];
    int excl = chunk_base + wbase + (x - v);
    if (i < n) { off[i] = excl; cursor[i] = excl; }
    int total = wsum[15];
    __syncthreads();
    if (t == 0) chunk_base += total;
    __syncthreads();
  }
  if (t == 0) off[n] = chunk_base;
}

// sort edges by dst: ssrc/sdst/seattr in segment order
__global__ __launch_bounds__(256) void place_kernel(const int* __restrict__ srcv,
                                                    const int* __restrict__ dstv,
                                                    const float* __restrict__ eattr,
                                                    int* __restrict__ cursor,
                                                    int* __restrict__ ssrc,
                                                    int* __restrict__ sdst,
                                                    float* __restrict__ seattr, int E) {
  int e = blockIdx.x * 256 + threadIdx.x;
  if (e < E) {
    int d = dstv[e];
    int p = atomicAdd(&cursor[d], 1);
    ssrc[p] = srcv[e];
    sdst[p] = d;
    seattr[p * 3 + 0] = eattr[e * 3 + 0];
    seattr[p * 3 + 1] = eattr[e * 3 + 1];
    seattr[p * 3 + 2] = eattr[e * 3 + 2];
  }
}

// ---------------- weight transpose f32 -> bf16, WT[n][k] = W[k][n] ----------------
__global__ __launch_bounds__(256) void wt_kernel(
    const float* __restrict__ l0_We, const float* __restrict__ We,
    const float* __restrict__ Wl, const float* __restrict__ Wr,
    unsigned short* __restrict__ WeT, unsigned short* __restrict__ WlT,
    unsigned short* __restrict__ WrT) {
  int b = blockIdx.x, t = threadIdx.x;
  const float* src;
  unsigned short* dst;
  if (b == 0)      { src = l0_We;                dst = WeT; }
  else if (b < 4)  { src = We + (b - 1) * 16384; dst = WeT + b * 16384; }
  else if (b < 7)  { src = Wl + (b - 4) * 16384; dst = WlT + (b - 4) * 16384; }
  else             { src = Wr + (b - 7) * 16384; dst = WrT + (b - 7) * 16384; }
  int n = t >> 1, k0 = (t & 1) * 64;
  #pragma unroll
  for (int k = 0; k < 64; ++k)
    dst[n * 128 + k0 + k] = f2bf(src[(k0 + k) * 128 + n]);
}

// ---------------- layer-0 node projection (K = 12) -> bf16 ----------------
__global__ __launch_bounds__(256) void node_proj0_kernel(
    const float* __restrict__ x,
    const float* __restrict__ Wl, const float* __restrict__ bl,
    const float* __restrict__ Wr, const float* __restrict__ br,
    unsigned short* __restrict__ xl, unsigned short* __restrict__ xr, int N) {
  int idx = blockIdx.x * 256 + threadIdx.x;
  int node = idx >> 7, col = idx & 127;
  if (node >= N) return;
  float al = bl[col], ar = br[col];
  const float* xrow = x + node * 12;
  #pragma unroll
  for (int k = 0; k < 12; ++k) {
    float xv = xrow[k];
    al += xv * Wl[k * 128 + col];
    ar += xv * Wr[k * 128 + col];
  }
  xl[idx] = f2bf(al);
  xr[idx] = f2bf(ar);
}

// ---------------- node projection MFMA: xl = h@Wl+bl, xr = h@Wr+br ----------------
__global__ __launch_bounds__(256) void node_proj_kernel(
    const unsigned short* __restrict__ hbf,
    const unsigned short* __restrict__ WlT, const float* __restrict__ bl,
    const unsigned short* __restrict__ WrT, const float* __restrict__ br,
    unsigned short* __restrict__ xl, unsigned short* __restrict__ xr, int N) {
  __shared__ unsigned short A_sh[64 * 136];
  int t = threadIdx.x;
  int nb = blockIdx.x * 64;
  #pragma unroll
  for (int it = 0; it < 4; ++it) {
    int idx = it * 256 + t;
    int row = idx >> 4, chunk = idx & 15;
    int ng = nb + row;
    float4 v = make_float4(0.f, 0.f, 0.f, 0.f);
    if (ng < N) v = *(const float4*)(hbf + ng * 128 + chunk * 8);
    *(float4*)(A_sh + row * 136 + chunk * 8) = v;
  }
  __syncthreads();
  int lane = t & 63, w = t >> 6;
  int m = lane & 15, quad = lane >> 4;
  bf16x8 afr[4];
  #pragma unroll
  for (int s = 0; s < 4; ++s)
    afr[s] = *(const bf16x8*)(A_sh + (w * 16 + m) * 136 + s * 32 + quad * 8);
  #pragma unroll
  for (int part = 0; part < 2; ++part) {
    const unsigned short* Bt = part ? WrT : WlT;
    const float* bias = part ? br : bl;
    unsigned short* out = part ? xr : xl;
    f32x4 acc[8];
    #pragma unroll
    for (int tt = 0; tt < 8; ++tt)
      #pragma unroll
      for (int r = 0; r < 4; ++r) acc[tt][r] = 0.f;
    #pragma unroll
    for (int tt = 0; tt < 8; ++tt)
      #pragma unroll
      for (int s = 0; s < 4; ++s) {
        bf16x8 b = *(const bf16x8*)(Bt + (tt * 16 + m) * 128 + s * 32 + quad * 8);
        acc[tt] = __builtin_amdgcn_mfma_f32_16x16x32_bf16(afr[s], b, acc[tt], 0, 0, 0);
      }
    #pragma unroll
    for (int tt = 0; tt < 8; ++tt) {
      int col = tt * 16 + m;
      float bv = bias[col];
      #pragma unroll
      for (int r = 0; r < 4; ++r) {
        int ng = nb + w * 16 + quad * 4 + r;
        if (ng < N) out[ng * 128 + col] = f2bf(acc[tt][r] + bv);
      }
    }
  }
}

// ---------------- fused edge-score kernel (lane-per-edge epilogue) ----------------
// block = 64 sorted edges, 4 waves x 16 edges. D[channel][edge] = WeT . esilu.
// B-operand lane mapping: lane (n=lane&15 -> edge, quad) supplies
// esilu[edge][k=quad*8+j] -- computed in registers from 3 edge attrs.
// C layout: col = lane&15 = edge-in-wave, row = quad*4 + r (+16*tt) = channel.
__global__ __launch_bounds__(256) void edge_score_kernel(
    const float* __restrict__ seattr,        // E x 3 (sorted)
    const float* __restrict__ Pw,            // 3 x 128
    const float* __restrict__ Pb,            // 128
    const unsigned short* __restrict__ WeT,  // 128 x 128 bf16 [n][k]
    const float* __restrict__ attw,          // 128
    const unsigned short* __restrict__ xl, const unsigned short* __restrict__ xr,
    const int* __restrict__ ssrc, const int* __restrict__ sdst,
    float* __restrict__ scores, int E) {
  int t = threadIdx.x;
  int eb = blockIdx.x * 64;
  int lane = t & 63, w = t >> 6;
  int m = lane & 15, quad = lane >> 4;
  int eg = eb + w * 16 + m;
  int egc = (eg < E) ? eg : (E - 1);

  // this lane's edge attrs + gather-row pointers (issue early)
  float ea0 = seattr[egc * 3], ea1 = seattr[egc * 3 + 1], ea2 = seattr[egc * 3 + 2];
  int sv = ssrc[egc], dv = sdst[egc];
  const unsigned short* xlrow = xl + (size_t)sv * 128;
  const unsigned short* xrrow = xr + (size_t)dv * 128;

  // B-fragments: silu(ea @ Pw + Pb) channels k = s*32 + quad*8 + j, in regs
  bf16x8 bfr[4];
  #pragma unroll
  for (int s = 0; s < 4; ++s) {
    int c0 = s * 32 + quad * 8;
    union { bf16x8 v; unsigned short u[8]; } bf;
    #pragma unroll
    for (int half = 0; half < 2; ++half) {
      float4 p0 = *(const float4*)(Pw + c0 + half * 4);
      float4 p1 = *(const float4*)(Pw + 128 + c0 + half * 4);
      float4 p2 = *(const float4*)(Pw + 256 + c0 + half * 4);
      float4 pb = *(const float4*)(Pb + c0 + half * 4);
      float z0 = ea0 * p0.x + ea1 * p1.x + ea2 * p2.x + pb.x;
      float z1 = ea0 * p0.y + ea1 * p1.y + ea2 * p2.y + pb.y;
      float z2 = ea0 * p0.z + ea1 * p1.z + ea2 * p2.z + pb.z;
      float z3 = ea0 * p0.w + ea1 * p1.w + ea2 * p2.w + pb.w;
      bf.u[half * 4 + 0] = f2bf(z0 / (1.f + __expf(-z0)));
      bf.u[half * 4 + 1] = f2bf(z1 / (1.f + __expf(-z1)));
      bf.u[half * 4 + 2] = f2bf(z2 / (1.f + __expf(-z2)));
      bf.u[half * 4 + 3] = f2bf(z3 / (1.f + __expf(-z3)));
    }
    bfr[s] = bf.v;
  }

  f32x4 acc[8];
  #pragma unroll
  for (int tt = 0; tt < 8; ++tt)
    #pragma unroll
    for (int r = 0; r < 4; ++r) acc[tt][r] = 0.f;
  #pragma unroll
  for (int tt = 0; tt < 8; ++tt)
    #pragma unroll
    for (int s = 0; s < 4; ++s) {
      bf16x8 a = *(const bf16x8*)(WeT + (tt * 16 + m) * 128 + s * 32 + quad * 8);
      acc[tt] = __builtin_amdgcn_mfma_f32_16x16x32_bf16(a, bfr[s], acc[tt], 0, 0, 0);
    }

  // epilogue: each lane owns one edge, channels tt*16 + quad*4 + r
  float psum[4] = {0.f, 0.f, 0.f, 0.f};
  #pragma unroll
  for (int tt = 0; tt < 8; ++tt) {
    int c0 = tt * 16 + quad * 4;
    ushort4 xlv = *(const ushort4*)(xlrow + c0);
    ushort4 xrv = *(const ushort4*)(xrrow + c0);
    float4 at = *(const float4*)(attw + c0);
    int h = tt >> 1;
    float v0 = acc[tt][0] + bf2f(xlv.x) + bf2f(xrv.x);
    float v1 = acc[tt][1] + bf2f(xlv.y) + bf2f(xrv.y);
    float v2 = acc[tt][2] + bf2f(xlv.z) + bf2f(xrv.z);
    float v3 = acc[tt][3] + bf2f(xlv.w) + bf2f(xrv.w);
    v0 = fmaxf(v0, 0.2f * v0);
    v1 = fmaxf(v1, 0.2f * v1);
    v2 = fmaxf(v2, 0.2f * v2);
    v3 = fmaxf(v3, 0.2f * v3);
    psum[h] += v0 * at.x + v1 * at.y + v2 * at.z + v3 * at.w;
  }
  #pragma unroll
  for (int h = 0; h < 4; ++h) {
    psum[h] += __shfl_xor(psum[h], 16, 64);
    psum[h] += __shfl_xor(psum[h], 32, 64);
  }
  if (quad == 0 && eg < E) {
    float4 sc; sc.x = psum[0]; sc.y = psum[1]; sc.z = psum[2]; sc.w = psum[3];
    *(float4*)(scores + (size_t)eg * 4) = sc;
  }
}

// ---------------- aggregation: pipelined online softmax + LN + silu + residual ----------------
__global__ __launch_bounds__(256) void aggregate_kernel(
    const unsigned short* __restrict__ xl, const float* __restrict__ scores,
    const int* __restrict__ off, const int* __restrict__ ssrc,
    const float* __restrict__ bias,
    const float* __restrict__ lng, const float* __restrict__ lnb,
    const float* __restrict__ h_in, float* __restrict__ h_out,
    unsigned short* __restrict__ hbf_out, int N) {
  int wid = threadIdx.x >> 6, lane = threadIdx.x & 63;
  int n = blockIdx.x * 4 + wid;
  if (n >= N) return;
  int hh = lane >> 4;
  int p0 = off[n], p1 = off[n + 1];
  float rm = -3.0e38f, rden = 0.f, a0 = 0.f, a1 = 0.f;
  float s_nxt = 0.f;
  ushort2 xv_nxt = make_ushort2(0, 0);
  if (p0 < p1) {
    s_nxt = scores[(size_t)p0 * 4 + hh];
    xv_nxt = *(const ushort2*)(xl + (size_t)ssrc[p0] * 128 + lane * 2);
  }
  for (int p = p0; p < p1; ++p) {
    float s = s_nxt;
    ushort2 xv = xv_nxt;
    if (p + 1 < p1) {
      s_nxt = scores[(size_t)(p + 1) * 4 + hh];
      xv_nxt = *(const ushort2*)(xl + (size_t)ssrc[p + 1] * 128 + lane * 2);
    }
    float mn = fmaxf(rm, s);
    float c = __expf(rm - mn);
    float wgt = __expf(s - mn);
    rden = rden * c + wgt;
    a0 = a0 * c + wgt * bf2f(xv.x);
    a1 = a1 * c + wgt * bf2f(xv.y);
    rm = mn;
  }
  float inv = 1.f / (rden + 1e-16f);
  const float2 bb = *(const float2*)(bias + lane * 2);
  float v0 = a0 * inv + bb.x;
  float v1 = a1 * inv + bb.y;
  float s1 = v0 + v1, s2 = v0 * v0 + v1 * v1;
  #pragma unroll
  for (int o = 1; o < 64; o <<= 1) {
    s1 += __shfl_xor(s1, o, 64);
    s2 += __shfl_xor(s2, o, 64);
  }
  float mean = s1 * (1.f / 128.f);
  float var = s2 * (1.f / 128.f) - mean * mean;
  float rs = rsqrtf(var + 1e-5f);
  const float2 g2 = *(const float2*)(lng + lane * 2);
  const float2 b2 = *(const float2*)(lnb + lane * 2);
  float y0 = (v0 - mean) * rs * g2.x + b2.x;
  float y1 = (v1 - mean) * rs * g2.y + b2.y;
  float o0 = y0 / (1.f + __expf(-y0));
  float o1 = y1 / (1.f + __expf(-y1));
  if (h_in) {
    const float2 hv = *(const float2*)(h_in + n * 128 + lane * 2);
    o0 += hv.x; o1 += hv.y;
  }
  float2 ov; ov.x = o0; ov.y = o1;
  *(float2*)(h_out + n * 128 + lane * 2) = ov;
  if (hbf_out) {
    ushort2 hb; hb.x = f2bf(o0); hb.y = f2bf(o1);
    *(ushort2*)(hbf_out + n * 128 + lane * 2) = hb;
  }
}

// ---------------------------------------------------------------------------
extern "C" void kernel_launch(void* const* d_in, const int* in_sizes, int n_in,
                              void* d_out, int out_size, void* d_ws, size_t ws_size,
                              hipStream_t stream) {
  const float* x       = (const float*)d_in[0];
  const int*   eidx    = (const int*)d_in[1];
  const float* eattr   = (const float*)d_in[2];
  const float* Pw      = (const float*)d_in[3];
  const float* Pb      = (const float*)d_in[4];
  const float* l0_Wl   = (const float*)d_in[5];
  const float* l0_bl   = (const float*)d_in[6];
  const float* l0_Wr   = (const float*)d_in[7];
  const float* l0_br   = (const float*)d_in[8];
  const float* l0_We   = (const float*)d_in[9];
  const float* l0_att  = (const float*)d_in[10];
  const float* l0_bias = (const float*)d_in[11];
  const float* Wl      = (const float*)d_in[12];
  const float* bl      = (const float*)d_in[13];
  const float* Wr      = (const float*)d_in[14];
  const float* br      = (const float*)d_in[15];
  const float* We      = (const float*)d_in[16];
  const float* att     = (const float*)d_in[17];
  const float* bias    = (const float*)d_in[18];
  const float* ln_g    = (const float*)d_in[19];
  const float* ln_b    = (const float*)d_in[20];
  (void)n_in; (void)out_size; (void)ws_size;

  int N = in_sizes[0] / 12;
  int E = in_sizes[2] / 3;
  const int* srcv = eidx;
  const int* dstv = eidx + E;

  char* w = (char*)d_ws;
  unsigned short* xl_bf = (unsigned short*)w; w += (size_t)N * 128 * 2;
  unsigned short* xr_bf = (unsigned short*)w; w += (size_t)N * 128 * 2;
  unsigned short* h_bf  = (unsigned short*)w; w += (size_t)N * 128 * 2;
  float* h      = (float*)w;  w += (size_t)N * 128 * 4;
  float* scores = (float*)w;  w += (size_t)E * 4 * 4;
  float* seattr = (float*)w;  w += (size_t)E * 3 * 4;
  int* ssrc   = (int*)w;      w += (size_t)E * 4;
  int* sdst   = (int*)w;      w += (size_t)E * 4;
  int* deg    = (int*)w;      w += (size_t)N * 4;
  int* off    = (int*)w;      w += (size_t)(N + 1) * 4;
  int* cursor = (int*)w;      w += (size_t)N * 4 + 12;  // keep 16B align
  unsigned short* WeT = (unsigned short*)w; w += (size_t)4 * 16384 * 2;
  unsigned short* WlT = (unsigned short*)w; w += (size_t)3 * 16384 * 2;
  unsigned short* WrT = (unsigned short*)w; w += (size_t)3 * 16384 * 2;

  hipMemsetAsync(deg, 0, (size_t)N * 4, stream);
  int gE = (E + 255) / 256;
  count_kernel<<<gE, 256, 0, stream>>>(dstv, deg, E);
  scan_kernel<<<1, 1024, 0, stream>>>(deg, off, cursor, N);
  place_kernel<<<gE, 256, 0, stream>>>(srcv, dstv, eattr, cursor, ssrc, sdst, seattr, E);
  wt_kernel<<<10, 256, 0, stream>>>(l0_We, We, Wl, Wr, WeT, WlT, WrT);

  dim3 egrid((E + 63) / 64);
  dim3 ngrid((N + 63) / 64);
  int agrid = (N + 3) / 4;

  // layer 0 (input dim 12, no residual)
  node_proj0_kernel<<<(N * 128 + 255) / 256, 256, 0, stream>>>(
      x, l0_Wl, l0_bl, l0_Wr, l0_br, xl_bf, xr_bf, N);
  edge_score_kernel<<<egrid, 256, 0, stream>>>(
      seattr, Pw, Pb, WeT, l0_att, xl_bf, xr_bf, ssrc, sdst, scores, E);
  aggregate_kernel<<<agrid, 256, 0, stream>>>(
      xl_bf, scores, off, ssrc, l0_bias, ln_g, ln_b, nullptr, h, h_bf, N);

  // layers 1..3 (residual)
  for (int i = 0; i < 3; ++i) {
    node_proj_kernel<<<ngrid, 256, 0, stream>>>(
        h_bf, WlT + i * 16384, bl + i * 128, WrT + i * 16384, br + i * 128,
        xl_bf, xr_bf, N);
    edge_score_kernel<<<egrid, 256, 0, stream>>>(
        seattr, Pw, Pb, WeT + (i + 1) * 16384, att + i * 128,
        xl_bf, xr_bf, ssrc, sdst, scores, E);
    float* hout = (i == 2) ? (float*)d_out : h;
    unsigned short* hbfout = (i == 2) ? nullptr : h_bf;
    aggregate_kernel<<<agrid, 256, 0, stream>>>(
        xl_bf, scores, off, ssrc, bias + i * 128,
        ln_g + (i + 1) * 128, ln_b + (i + 1) * 128, h, hout, hbfout, N);
  }
}